// Round 17
// baseline (390.329 us; speedup 1.0000x reference)
//
#include <hip/hip_runtime.h>

#define N_NODES 100000
#define N_EDGES 1600000
#define NBUCK   3125          // N_NODES / 32 exactly
#define BCAP    1024          // edges per bucket region (mean 512, 22-sigma safe)

typedef __attribute__((ext_vector_type(8))) _Float16 half8_t;
typedef __attribute__((ext_vector_type(4))) float f32x4_t;
typedef __attribute__((ext_vector_type(4))) _Float16 half4_t;
typedef __attribute__((ext_vector_type(2))) _Float16 half2_t;

// ---------------- bucketed CSR build ----------------
__global__ void bcur_init_kernel(int* __restrict__ bcur, int nb) {
    int b = blockIdx.x * blockDim.x + threadIdx.x;
    if (b < nb) bcur[b] = b * BCAP;
}

// phase 1: append (src,dst) into per-bucket regions
__global__ void bucket_kernel(const int* __restrict__ src, const int* __restrict__ dst,
                              int* __restrict__ bcur, int2* __restrict__ tmp, int E) {
    int i = blockIdx.x * blockDim.x + threadIdx.x;
    if (i >= E) return;
    int s = src[i], d = dst[i];
    int pos = atomicAdd(&bcur[d >> 5], 1);
    tmp[pos] = make_int2(s, d);
}

// per-bucket node-degree histogram (LDS atomics only)
__global__ __launch_bounds__(256) void bdeg_kernel(const int* __restrict__ bcur,
                                                   const int2* __restrict__ tmp,
                                                   int* __restrict__ deg, int n) {
    __shared__ int ld[32];
    int b = blockIdx.x, t = threadIdx.x;
    if (t < 32) ld[t] = 0;
    __syncthreads();
    int e1 = bcur[b];
    for (int e = b * BCAP + t; e < e1; e += 256)
        atomicAdd(&ld[tmp[e].y & 31], 1);
    __syncthreads();
    int node = b * 32 + t;
    if (t < 32 && node < n) deg[node] = ld[t];
}

// per-bucket exact placement into CSR (LDS cursors; 4KB contiguous write region)
__global__ __launch_bounds__(256) void place_kernel(const int* __restrict__ bcur,
                                                    const int2* __restrict__ tmp,
                                                    const int* __restrict__ rowptr,
                                                    const float* __restrict__ dinv,
                                                    int2* __restrict__ csr, int n) {
    __shared__ int lc[32];
    int b = blockIdx.x, t = threadIdx.x;
    if (t < 32) lc[t] = 0;
    __syncthreads();
    int e1 = bcur[b];
    for (int e = b * BCAP + t; e < e1; e += 256) {
        int2 p = tmp[e];
        int pos = atomicAdd(&lc[p.y & 31], 1);
        float w = dinv[p.x] * dinv[p.y];
        csr[rowptr[p.y] + pos] = make_int2(p.x, __float_as_int(w));
    }
}

__global__ void dinv_kernel(const int* __restrict__ deg, float* __restrict__ dinv, int n) {
    int i = blockIdx.x * blockDim.x + threadIdx.x;
    if (i < n) dinv[i] = rsqrtf((float)(deg[i] + 1));   // +1 = self-loop
}

// ---------------- exclusive scan of deg -> rowptr (3 passes) ----------------
__global__ void scan_sums_kernel(const int* __restrict__ deg, int* __restrict__ bsums, int n) {
    __shared__ int sd[256];
    int t = threadIdx.x;
    int base = blockIdx.x * 1024 + t * 4;
    int s = 0;
    #pragma unroll
    for (int j = 0; j < 4; ++j) { int i = base + j; if (i < n) s += deg[i]; }
    sd[t] = s; __syncthreads();
    for (int off = 128; off > 0; off >>= 1) {
        if (t < off) sd[t] += sd[t + off];
        __syncthreads();
    }
    if (t == 0) bsums[blockIdx.x] = sd[0];
}

__global__ void scan_offsets_kernel(int* __restrict__ bsums, int nb, int* __restrict__ rowptr_tail) {
    __shared__ int sd[128];
    int t = threadIdx.x;
    int v = (t < nb) ? bsums[t] : 0;
    sd[t] = v; __syncthreads();
    for (int off = 1; off < 128; off <<= 1) {
        int x = (t >= off) ? sd[t - off] : 0;
        __syncthreads();
        sd[t] += x;
        __syncthreads();
    }
    if (t < nb) bsums[t] = sd[t] - v;      // exclusive
    if (t == 0) *rowptr_tail = N_EDGES;    // rowptr[n]
}

__global__ void scan_final_kernel(const int* __restrict__ deg, const int* __restrict__ bsums,
                                  int* __restrict__ rowptr, int n) {
    __shared__ int sd[256];
    int t = threadIdx.x;
    int base = blockIdx.x * 1024 + t * 4;
    int v[4], pre[4], s = 0;
    #pragma unroll
    for (int j = 0; j < 4; ++j) {
        int i = base + j;
        v[j] = (i < n) ? deg[i] : 0;
        pre[j] = s; s += v[j];
    }
    sd[t] = s;
    int mine = s;
    __syncthreads();
    for (int off = 1; off < 256; off <<= 1) {
        int x = (t >= off) ? sd[t - off] : 0;
        __syncthreads();
        sd[t] += x;
        __syncthreads();
    }
    int excl = sd[t] - mine + bsums[blockIdx.x];
    #pragma unroll
    for (int j = 0; j < 4; ++j) {
        int i = base + j;
        if (i < n) rowptr[i] = excl + pre[j];
    }
}

// ---------------- x -> fp16 plane ----------------
__global__ void x16_kernel(const float* __restrict__ x, _Float16* __restrict__ y, int total4) {
    int i = blockIdx.x * blockDim.x + threadIdx.x;
    if (i >= total4) return;
    float4 v = *(const float4*)&x[(size_t)i * 4];
    half4_t o;
    o[0] = (_Float16)v.x; o[1] = (_Float16)v.y;
    o[2] = (_Float16)v.z; o[3] = (_Float16)v.w;
    *(half4_t*)&y[(size_t)i * 4] = o;
}

// ---------------- W2fc = W2 @ Wfc -> transposed fp16 [48][256]; bfc2 = b2@Wfc+bfc --
__global__ __launch_bounds__(256) void w2fc_kernel(
        const float* __restrict__ W2, const float* __restrict__ Wfc,
        const float* __restrict__ b2, const float* __restrict__ bfc,
        _Float16* __restrict__ T16, float* __restrict__ bfc2) {
    __shared__ float wf[64 * 40];
    int t = threadIdx.x;
    for (int i = t; i < 64 * 40; i += 256) wf[i] = Wfc[i];
    __syncthreads();
    float acc[40];
    #pragma unroll
    for (int c = 0; c < 40; ++c) acc[c] = 0.f;
    for (int k = 0; k < 64; ++k) {
        float a = W2[t * 64 + k];
        #pragma unroll
        for (int c = 0; c < 40; ++c) acc[c] += a * wf[k * 40 + c];
    }
    #pragma unroll
    for (int c = 0; c < 40; ++c) T16[c * 256 + t] = (_Float16)acc[c];
    #pragma unroll
    for (int r = 40; r < 48; ++r) T16[r * 256 + t] = (_Float16)0.f;
    if (t < 40) {
        float s = bfc[t];
        for (int k = 0; k < 64; ++k) s += b2[k] * wf[k * 40 + t];
        bfc2[t] = s;
    }
}

// ---------------- W1 [128][256] -> W1t fp16 [256][128] ----------------
__global__ void w1t_kernel(const float* __restrict__ W1, _Float16* __restrict__ t16) {
    int k = blockIdx.x;          // 0..127
    int n = threadIdx.x;         // 0..255
    t16[n * 128 + k] = (_Float16)W1[k * 256 + n];
}

// ---------------- gather1: aggx(fp16) = A_hat @ x16 ----------------
__global__ void gather1_kernel(const int* __restrict__ rowptr, const int2* __restrict__ csr,
                               const float* __restrict__ dinv, const _Float16* __restrict__ x,
                               _Float16* __restrict__ o16, int n) {
    const int lane = threadIdx.x & 63;
    const int wid0 = (blockIdx.x * blockDim.x + threadIdx.x) >> 6;
    const int nwav = (gridDim.x * blockDim.x) >> 6;
    for (int node = wid0; node < n; node += nwav) {
        float di = dinv[node];
        float selfw = di * di;
        int e0 = rowptr[node], e1 = rowptr[node + 1];
        const half2_t sv = *(const half2_t*)&x[(size_t)node * 128 + lane * 2];
        float ax = (float)sv[0] * selfw, ay = (float)sv[1] * selfw;
        int e = e0;
        for (; e + 8 <= e1; e += 8) {
            int2 p[8]; half2_t v[8];
            #pragma unroll
            for (int u = 0; u < 8; ++u) p[u] = csr[e + u];
            #pragma unroll
            for (int u = 0; u < 8; ++u)
                v[u] = *(const half2_t*)&x[(size_t)p[u].x * 128 + lane * 2];
            #pragma unroll
            for (int u = 0; u < 8; ++u) {
                float w = __int_as_float(p[u].y);
                ax += (float)v[u][0] * w; ay += (float)v[u][1] * w;
            }
        }
        for (; e + 4 <= e1; e += 4) {
            int2 p[4]; half2_t v[4];
            #pragma unroll
            for (int u = 0; u < 4; ++u) p[u] = csr[e + u];
            #pragma unroll
            for (int u = 0; u < 4; ++u)
                v[u] = *(const half2_t*)&x[(size_t)p[u].x * 128 + lane * 2];
            #pragma unroll
            for (int u = 0; u < 4; ++u) {
                float w = __int_as_float(p[u].y);
                ax += (float)v[u][0] * w; ay += (float)v[u][1] * w;
            }
        }
        for (; e < e1; ++e) {
            int2 p = csr[e];
            float w = __int_as_float(p.y);
            const half2_t v = *(const half2_t*)&x[(size_t)p.x * 128 + lane * 2];
            ax += (float)v[0] * w; ay += (float)v[1] * w;
        }
        half2_t ov; ov[0] = (_Float16)ax; ov[1] = (_Float16)ay;
        *(half2_t*)&o16[(size_t)node * 128 + lane * 2] = ov;
    }
}

// ---------------- gather2 (F=40), bias fused, writes d_out ----------------
__global__ void gather2_kernel(const int* __restrict__ rowptr, const int2* __restrict__ csr,
                               const float* __restrict__ dinv, const float* __restrict__ xw,
                               const float* __restrict__ bias, float* __restrict__ out, int n) {
    const int lane = threadIdx.x & 63;
    const int wid0 = (blockIdx.x * blockDim.x + threadIdx.x) >> 6;
    const int nwav = (gridDim.x * blockDim.x) >> 6;
    const int cl = lane < 40 ? lane : 39;
    for (int node = wid0; node < n; node += nwav) {
        float di = dinv[node];
        float selfw = di * di;
        int e0 = rowptr[node], e1 = rowptr[node + 1];
        float acc = xw[(size_t)node * 40 + cl] * selfw;
        int e = e0;
        for (; e + 8 <= e1; e += 8) {
            int2 p[8]; float v[8];
            #pragma unroll
            for (int u = 0; u < 8; ++u) p[u] = csr[e + u];
            #pragma unroll
            for (int u = 0; u < 8; ++u) v[u] = xw[(size_t)p[u].x * 40 + cl];
            #pragma unroll
            for (int u = 0; u < 8; ++u) acc += v[u] * __int_as_float(p[u].y);
        }
        for (; e < e1; ++e) {
            int2 p = csr[e];
            acc += xw[(size_t)p.x * 40 + cl] * __int_as_float(p.y);
        }
        acc += bias[cl];
        if (lane < 40) out[(size_t)node * 40 + lane] = acc;
    }
}

// ---------------- gemm1: fp16 MFMA, LDS-staged ----------------
__global__ __launch_bounds__(256) void gemm1_mfma(
        const _Float16* __restrict__ A16, const _Float16* __restrict__ B16,
        const float* __restrict__ bias, _Float16* __restrict__ C16, int M) {
    constexpr int K = 128, N = 256, LDK = 40;
    __shared__ _Float16 sA[128 * LDK];
    __shared__ _Float16 sB[128 * LDK];
    const int t = threadIdx.x;
    const int m0 = blockIdx.x * 128, n0 = blockIdx.y * 128;
    const int wave = t >> 6, lane = t & 63;
    const int wm = wave >> 1, wn = wave & 1;
    const int l15 = lane & 15, k8 = (lane >> 4) * 8;

    f32x4_t acc[4][4] = {};

    for (int k0 = 0; k0 < K; k0 += 32) {
        #pragma unroll
        for (int u = 0; u < 2; ++u) {
            int idx = t + u * 256;
            int r = idx >> 2, c = (idx & 3) * 8;
            int gr = m0 + r; if (gr > M - 1) gr = M - 1;
            *(uint4*)&sA[r * LDK + c] = *(const uint4*)&A16[(size_t)gr * K + k0 + c];
            int bn = n0 + r;
            *(uint4*)&sB[r * LDK + c] = *(const uint4*)&B16[(size_t)bn * K + k0 + c];
        }
        __syncthreads();
        half8_t fa[4], fb[4];
        #pragma unroll
        for (int i = 0; i < 4; ++i) {
            int m = wm * 64 + i * 16 + l15;
            fa[i] = *(const half8_t*)&sA[m * LDK + k8];
            int nn = wn * 64 + i * 16 + l15;
            fb[i] = *(const half8_t*)&sB[nn * LDK + k8];
        }
        #pragma unroll
        for (int i = 0; i < 4; ++i)
            #pragma unroll
            for (int j = 0; j < 4; ++j)
                acc[i][j] = __builtin_amdgcn_mfma_f32_16x16x32_f16(fa[i], fb[j], acc[i][j], 0, 0, 0);
        __syncthreads();
    }

    const int r4 = (lane >> 4) * 4;
    #pragma unroll
    for (int j = 0; j < 4; ++j) {
        int col = n0 + wn * 64 + j * 16 + l15;
        float bv = bias[col];
        #pragma unroll
        for (int i = 0; i < 4; ++i) {
            #pragma unroll
            for (int r = 0; r < 4; ++r) {
                int row = m0 + wm * 64 + i * 16 + r4 + r;
                if (row < M) {
                    float v = fmaxf(acc[i][j][r] + bv, 0.f);
                    C16[(size_t)row * N + col] = (_Float16)v;
                }
            }
        }
    }
}

// ---------------- gemm2: fp16 MFMA, LDS-staged ----------------
__global__ __launch_bounds__(256) void gemm2_mfma(
        const _Float16* __restrict__ A16, const _Float16* __restrict__ B16,
        float* __restrict__ C, int M) {
    constexpr int K = 256, LDK = 40;
    __shared__ _Float16 sA[128 * LDK];
    __shared__ _Float16 sB[48 * LDK];
    const int t = threadIdx.x;
    const int m0 = blockIdx.x * 128;
    const int wave = t >> 6, lane = t & 63;
    const int l15 = lane & 15, k8 = (lane >> 4) * 8;

    f32x4_t acc[2][3] = {};

    for (int k0 = 0; k0 < K; k0 += 32) {
        #pragma unroll
        for (int u = 0; u < 2; ++u) {
            int idx = t + u * 256;
            int r = idx >> 2, c = (idx & 3) * 8;
            int gr = m0 + r; if (gr > M - 1) gr = M - 1;
            *(uint4*)&sA[r * LDK + c] = *(const uint4*)&A16[(size_t)gr * K + k0 + c];
        }
        if (t < 192) {
            int r = t >> 2, c = (t & 3) * 8;
            *(uint4*)&sB[r * LDK + c] = *(const uint4*)&B16[(size_t)r * K + k0 + c];
        }
        __syncthreads();
        half8_t fa[2], fb[3];
        #pragma unroll
        for (int i = 0; i < 2; ++i) {
            int m = wave * 32 + i * 16 + l15;
            fa[i] = *(const half8_t*)&sA[m * LDK + k8];
        }
        #pragma unroll
        for (int j = 0; j < 3; ++j) {
            int nn = j * 16 + l15;
            fb[j] = *(const half8_t*)&sB[nn * LDK + k8];
        }
        #pragma unroll
        for (int i = 0; i < 2; ++i)
            #pragma unroll
            for (int j = 0; j < 3; ++j)
                acc[i][j] = __builtin_amdgcn_mfma_f32_16x16x32_f16(fa[i], fb[j], acc[i][j], 0, 0, 0);
        __syncthreads();
    }

    const int r4 = (lane >> 4) * 4;
    #pragma unroll
    for (int i = 0; i < 2; ++i)
        #pragma unroll
        for (int j = 0; j < 3; ++j) {
            int col = j * 16 + l15;
            if (col < 40) {
                #pragma unroll
                for (int r = 0; r < 4; ++r) {
                    int row = m0 + wave * 32 + i * 16 + r4 + r;
                    if (row < M) C[(size_t)row * 40 + col] = acc[i][j][r];
                }
            }
        }
}

extern "C" void kernel_launch(void* const* d_in, const int* in_sizes, int n_in,
                              void* d_out, int out_size, void* d_ws, size_t ws_size,
                              hipStream_t stream) {
    const float* x   = (const float*)d_in[0];
    const int*   ei  = (const int*)d_in[1];
    const float* W1  = (const float*)d_in[2];
    const float* b1  = (const float*)d_in[3];
    const float* W2  = (const float*)d_in[4];
    const float* b2  = (const float*)d_in[5];
    const float* Wfc = (const float*)d_in[6];
    const float* bfc = (const float*)d_in[7];
    float* out = (float*)d_out;

    const int n = N_NODES, E = N_EDGES;
    const int* src = ei;
    const int* dst = ei + E;

    char* ws = (char*)d_ws;
    int*       deg    = (int*)(ws + 0);            // 400 KB
    float*     dinv   = (float*)(ws + 409600);     // 400 KB
    int*       rowptr = (int*)(ws + 819200);       // ~400 KB
    int*       bsums  = (int*)(ws + 1219584);      // 512 B
    float*     bfc2   = (float*)(ws + 1220096);    // 512 B
    _Float16*  w2t16  = (_Float16*)(ws + 1220608); // 24 KB [48][256]
    _Float16*  w1t16  = (_Float16*)(ws + 1245184); // 64 KB [256][128]
    int*       bcur   = (int*)(ws + 1310720);      // 12.5 KB (pad to 1323520)
    int2*      csr    = (int2*)(ws + 1323520);     // 12.8 MB
    int2*      tmp    = (int2*)(ws + 14123520);    // 25.6 MB (bucket regions)
    _Float16*  x16    = (_Float16*)(ws + 39723520);  // 25.6 MB
    _Float16*  aggx16 = (_Float16*)(ws + 65323520);  // 25.6 MB
    _Float16*  h116   = (_Float16*)(ws + 90923520);  // 51.2 MB
    float*     h1w    = (float*)(ws + 142123520);    // 16 MB ([100k][40])

    const int nb = (n + 1023) / 1024;  // 98 scan blocks

    // ---- bucketed CSR build (no global-histogram atomics, no memsets) ----
    bcur_init_kernel<<<(NBUCK + 255) / 256, 256, 0, stream>>>(bcur, NBUCK);
    bucket_kernel<<<(E + 255) / 256, 256, 0, stream>>>(src, dst, bcur, tmp, E);
    bdeg_kernel<<<NBUCK, 256, 0, stream>>>(bcur, tmp, deg, n);
    dinv_kernel<<<(n + 255) / 256, 256, 0, stream>>>(deg, dinv, n);
    scan_sums_kernel<<<nb, 256, 0, stream>>>(deg, bsums, n);
    scan_offsets_kernel<<<1, 128, 0, stream>>>(bsums, nb, rowptr + n);
    scan_final_kernel<<<nb, 256, 0, stream>>>(deg, bsums, rowptr, n);
    place_kernel<<<NBUCK, 256, 0, stream>>>(bcur, tmp, rowptr, dinv, csr, n);

    // ---- weight precomputes + x fp16 plane ----
    w2fc_kernel<<<1, 256, 0, stream>>>(W2, Wfc, b2, bfc, w2t16, bfc2);
    w1t_kernel<<<128, 256, 0, stream>>>(W1, w1t16);
    x16_kernel<<<(n * 128 / 4 + 255) / 256, 256, 0, stream>>>(x, x16, n * 32);

    // ---- layer 1: aggx(fp16) = A_hat @ x16; h1(fp16) = relu(aggx @ W1 + b1) ----
    gather1_kernel<<<2048, 256, 0, stream>>>(rowptr, csr, dinv, x16, aggx16, n);
    gemm1_mfma<<<dim3((n + 127) / 128, 2), 256, 0, stream>>>(
        aggx16, w1t16, b1, h116, n);

    // ---- layer 2 + FC folded: out = A_hat @ (h1 @ W2fc) + bfc2 ----
    gemm2_mfma<<<(n + 127) / 128, 256, 0, stream>>>(h116, w2t16, h1w, n);
    gather2_kernel<<<2048, 256, 0, stream>>>(rowptr, csr, dinv, h1w, bfc2, out, n);
}

// Round 18
// 347.567 us; speedup vs baseline: 1.1230x; 1.1230x over previous
//
#include <hip/hip_runtime.h>

#define N_NODES 100000
#define N_EDGES 1600000
#define NBUCK   3125          // N_NODES / 32 exactly
#define NGRP    8             // XCD shards per bucket (blockIdx & 7)
#define GCAP    128           // per (bucket,group): mean 64, 8-sigma safe

typedef __attribute__((ext_vector_type(8))) _Float16 half8_t;
typedef __attribute__((ext_vector_type(4))) float f32x4_t;
typedef __attribute__((ext_vector_type(4))) _Float16 half4_t;
typedef __attribute__((ext_vector_type(2))) _Float16 half2_t;

// ---------------- bucketed CSR build (XCD-sharded) ----------------
__global__ void bcur_init_kernel(int* __restrict__ bcur, int nc) {
    int i = blockIdx.x * blockDim.x + threadIdx.x;
    if (i < nc) bcur[i] = i * GCAP;
}

// phase 1: append (src,dst) into per-(bucket,group) regions; group = blockIdx&7
// so each region's head lines are written by one XCD only (write-amp ~1x).
__global__ void bucket_kernel(const int* __restrict__ src, const int* __restrict__ dst,
                              int* __restrict__ bcur, int2* __restrict__ tmp, int E) {
    int i = blockIdx.x * blockDim.x + threadIdx.x;
    if (i >= E) return;
    int g = blockIdx.x & (NGRP - 1);
    int s = src[i], d = dst[i];
    int pos = atomicAdd(&bcur[(d >> 5) * NGRP + g], 1);
    tmp[pos] = make_int2(s, d);
}

// per-bucket node-degree histogram (LDS atomics only)
__global__ __launch_bounds__(256) void bdeg_kernel(const int* __restrict__ bcur,
                                                   const int2* __restrict__ tmp,
                                                   int* __restrict__ deg, int n) {
    __shared__ int ld[32];
    int b = blockIdx.x, t = threadIdx.x;
    if (t < 32) ld[t] = 0;
    __syncthreads();
    for (int g = 0; g < NGRP; ++g) {
        int base = (b * NGRP + g) * GCAP;
        int e1 = bcur[b * NGRP + g];
        for (int e = base + t; e < e1; e += 256)
            atomicAdd(&ld[tmp[e].y & 31], 1);
    }
    __syncthreads();
    int node = b * 32 + t;
    if (t < 32 && node < n) deg[node] = ld[t];
}

// per-bucket exact placement into CSR (LDS cursors; contiguous write region)
__global__ __launch_bounds__(256) void place_kernel(const int* __restrict__ bcur,
                                                    const int2* __restrict__ tmp,
                                                    const int* __restrict__ rowptr,
                                                    const float* __restrict__ dinv,
                                                    int2* __restrict__ csr, int n) {
    __shared__ int lc[32];
    int b = blockIdx.x, t = threadIdx.x;
    if (t < 32) lc[t] = 0;
    __syncthreads();
    for (int g = 0; g < NGRP; ++g) {
        int base = (b * NGRP + g) * GCAP;
        int e1 = bcur[b * NGRP + g];
        for (int e = base + t; e < e1; e += 256) {
            int2 p = tmp[e];
            int pos = atomicAdd(&lc[p.y & 31], 1);
            float w = dinv[p.x] * dinv[p.y];
            csr[rowptr[p.y] + pos] = make_int2(p.x, __float_as_int(w));
        }
    }
}

__global__ void dinv_kernel(const int* __restrict__ deg, float* __restrict__ dinv, int n) {
    int i = blockIdx.x * blockDim.x + threadIdx.x;
    if (i < n) dinv[i] = rsqrtf((float)(deg[i] + 1));   // +1 = self-loop
}

// ---------------- exclusive scan of deg -> rowptr (3 passes) ----------------
__global__ void scan_sums_kernel(const int* __restrict__ deg, int* __restrict__ bsums, int n) {
    __shared__ int sd[256];
    int t = threadIdx.x;
    int base = blockIdx.x * 1024 + t * 4;
    int s = 0;
    #pragma unroll
    for (int j = 0; j < 4; ++j) { int i = base + j; if (i < n) s += deg[i]; }
    sd[t] = s; __syncthreads();
    for (int off = 128; off > 0; off >>= 1) {
        if (t < off) sd[t] += sd[t + off];
        __syncthreads();
    }
    if (t == 0) bsums[blockIdx.x] = sd[0];
}

__global__ void scan_offsets_kernel(int* __restrict__ bsums, int nb, int* __restrict__ rowptr_tail) {
    __shared__ int sd[128];
    int t = threadIdx.x;
    int v = (t < nb) ? bsums[t] : 0;
    sd[t] = v; __syncthreads();
    for (int off = 1; off < 128; off <<= 1) {
        int x = (t >= off) ? sd[t - off] : 0;
        __syncthreads();
        sd[t] += x;
        __syncthreads();
    }
    if (t < nb) bsums[t] = sd[t] - v;      // exclusive
    if (t == 0) *rowptr_tail = N_EDGES;    // rowptr[n]
}

__global__ void scan_final_kernel(const int* __restrict__ deg, const int* __restrict__ bsums,
                                  int* __restrict__ rowptr, int n) {
    __shared__ int sd[256];
    int t = threadIdx.x;
    int base = blockIdx.x * 1024 + t * 4;
    int v[4], pre[4], s = 0;
    #pragma unroll
    for (int j = 0; j < 4; ++j) {
        int i = base + j;
        v[j] = (i < n) ? deg[i] : 0;
        pre[j] = s; s += v[j];
    }
    sd[t] = s;
    int mine = s;
    __syncthreads();
    for (int off = 1; off < 256; off <<= 1) {
        int x = (t >= off) ? sd[t - off] : 0;
        __syncthreads();
        sd[t] += x;
        __syncthreads();
    }
    int excl = sd[t] - mine + bsums[blockIdx.x];
    #pragma unroll
    for (int j = 0; j < 4; ++j) {
        int i = base + j;
        if (i < n) rowptr[i] = excl + pre[j];
    }
}

// ---------------- x -> fp16 plane ----------------
__global__ void x16_kernel(const float* __restrict__ x, _Float16* __restrict__ y, int total4) {
    int i = blockIdx.x * blockDim.x + threadIdx.x;
    if (i >= total4) return;
    float4 v = *(const float4*)&x[(size_t)i * 4];
    half4_t o;
    o[0] = (_Float16)v.x; o[1] = (_Float16)v.y;
    o[2] = (_Float16)v.z; o[3] = (_Float16)v.w;
    *(half4_t*)&y[(size_t)i * 4] = o;
}

// ---------------- W2fc = W2 @ Wfc -> transposed fp16 [48][256]; bfc2 = b2@Wfc+bfc --
__global__ __launch_bounds__(256) void w2fc_kernel(
        const float* __restrict__ W2, const float* __restrict__ Wfc,
        const float* __restrict__ b2, const float* __restrict__ bfc,
        _Float16* __restrict__ T16, float* __restrict__ bfc2) {
    __shared__ float wf[64 * 40];
    int t = threadIdx.x;
    for (int i = t; i < 64 * 40; i += 256) wf[i] = Wfc[i];
    __syncthreads();
    float acc[40];
    #pragma unroll
    for (int c = 0; c < 40; ++c) acc[c] = 0.f;
    for (int k = 0; k < 64; ++k) {
        float a = W2[t * 64 + k];
        #pragma unroll
        for (int c = 0; c < 40; ++c) acc[c] += a * wf[k * 40 + c];
    }
    #pragma unroll
    for (int c = 0; c < 40; ++c) T16[c * 256 + t] = (_Float16)acc[c];
    #pragma unroll
    for (int r = 40; r < 48; ++r) T16[r * 256 + t] = (_Float16)0.f;
    if (t < 40) {
        float s = bfc[t];
        for (int k = 0; k < 64; ++k) s += b2[k] * wf[k * 40 + t];
        bfc2[t] = s;
    }
}

// ---------------- W1 [128][256] -> W1t fp16 [256][128] ----------------
__global__ void w1t_kernel(const float* __restrict__ W1, _Float16* __restrict__ t16) {
    int k = blockIdx.x;          // 0..127
    int n = threadIdx.x;         // 0..255
    t16[n * 128 + k] = (_Float16)W1[k * 256 + n];
}

// ---------------- gather1: aggx(fp16) = A_hat @ x16 ----------------
__global__ void gather1_kernel(const int* __restrict__ rowptr, const int2* __restrict__ csr,
                               const float* __restrict__ dinv, const _Float16* __restrict__ x,
                               _Float16* __restrict__ o16, int n) {
    const int lane = threadIdx.x & 63;
    const int wid0 = (blockIdx.x * blockDim.x + threadIdx.x) >> 6;
    const int nwav = (gridDim.x * blockDim.x) >> 6;
    for (int node = wid0; node < n; node += nwav) {
        float di = dinv[node];
        float selfw = di * di;
        int e0 = rowptr[node], e1 = rowptr[node + 1];
        const half2_t sv = *(const half2_t*)&x[(size_t)node * 128 + lane * 2];
        float ax = (float)sv[0] * selfw, ay = (float)sv[1] * selfw;
        int e = e0;
        for (; e + 8 <= e1; e += 8) {
            int2 p[8]; half2_t v[8];
            #pragma unroll
            for (int u = 0; u < 8; ++u) p[u] = csr[e + u];
            #pragma unroll
            for (int u = 0; u < 8; ++u)
                v[u] = *(const half2_t*)&x[(size_t)p[u].x * 128 + lane * 2];
            #pragma unroll
            for (int u = 0; u < 8; ++u) {
                float w = __int_as_float(p[u].y);
                ax += (float)v[u][0] * w; ay += (float)v[u][1] * w;
            }
        }
        for (; e + 4 <= e1; e += 4) {
            int2 p[4]; half2_t v[4];
            #pragma unroll
            for (int u = 0; u < 4; ++u) p[u] = csr[e + u];
            #pragma unroll
            for (int u = 0; u < 4; ++u)
                v[u] = *(const half2_t*)&x[(size_t)p[u].x * 128 + lane * 2];
            #pragma unroll
            for (int u = 0; u < 4; ++u) {
                float w = __int_as_float(p[u].y);
                ax += (float)v[u][0] * w; ay += (float)v[u][1] * w;
            }
        }
        for (; e < e1; ++e) {
            int2 p = csr[e];
            float w = __int_as_float(p.y);
            const half2_t v = *(const half2_t*)&x[(size_t)p.x * 128 + lane * 2];
            ax += (float)v[0] * w; ay += (float)v[1] * w;
        }
        half2_t ov; ov[0] = (_Float16)ax; ov[1] = (_Float16)ay;
        *(half2_t*)&o16[(size_t)node * 128 + lane * 2] = ov;
    }
}

// ---------------- gather2 (F=40), bias fused, writes d_out ----------------
__global__ void gather2_kernel(const int* __restrict__ rowptr, const int2* __restrict__ csr,
                               const float* __restrict__ dinv, const float* __restrict__ xw,
                               const float* __restrict__ bias, float* __restrict__ out, int n) {
    const int lane = threadIdx.x & 63;
    const int wid0 = (blockIdx.x * blockDim.x + threadIdx.x) >> 6;
    const int nwav = (gridDim.x * blockDim.x) >> 6;
    const int cl = lane < 40 ? lane : 39;
    for (int node = wid0; node < n; node += nwav) {
        float di = dinv[node];
        float selfw = di * di;
        int e0 = rowptr[node], e1 = rowptr[node + 1];
        float acc = xw[(size_t)node * 40 + cl] * selfw;
        int e = e0;
        for (; e + 8 <= e1; e += 8) {
            int2 p[8]; float v[8];
            #pragma unroll
            for (int u = 0; u < 8; ++u) p[u] = csr[e + u];
            #pragma unroll
            for (int u = 0; u < 8; ++u) v[u] = xw[(size_t)p[u].x * 40 + cl];
            #pragma unroll
            for (int u = 0; u < 8; ++u) acc += v[u] * __int_as_float(p[u].y);
        }
        for (; e < e1; ++e) {
            int2 p = csr[e];
            acc += xw[(size_t)p.x * 40 + cl] * __int_as_float(p.y);
        }
        acc += bias[cl];
        if (lane < 40) out[(size_t)node * 40 + lane] = acc;
    }
}

// ---------------- gemm1: fp16 MFMA, LDS-staged ----------------
__global__ __launch_bounds__(256) void gemm1_mfma(
        const _Float16* __restrict__ A16, const _Float16* __restrict__ B16,
        const float* __restrict__ bias, _Float16* __restrict__ C16, int M) {
    constexpr int K = 128, N = 256, LDK = 40;
    __shared__ _Float16 sA[128 * LDK];
    __shared__ _Float16 sB[128 * LDK];
    const int t = threadIdx.x;
    const int m0 = blockIdx.x * 128, n0 = blockIdx.y * 128;
    const int wave = t >> 6, lane = t & 63;
    const int wm = wave >> 1, wn = wave & 1;
    const int l15 = lane & 15, k8 = (lane >> 4) * 8;

    f32x4_t acc[4][4] = {};

    for (int k0 = 0; k0 < K; k0 += 32) {
        #pragma unroll
        for (int u = 0; u < 2; ++u) {
            int idx = t + u * 256;
            int r = idx >> 2, c = (idx & 3) * 8;
            int gr = m0 + r; if (gr > M - 1) gr = M - 1;
            *(uint4*)&sA[r * LDK + c] = *(const uint4*)&A16[(size_t)gr * K + k0 + c];
            int bn = n0 + r;
            *(uint4*)&sB[r * LDK + c] = *(const uint4*)&B16[(size_t)bn * K + k0 + c];
        }
        __syncthreads();
        half8_t fa[4], fb[4];
        #pragma unroll
        for (int i = 0; i < 4; ++i) {
            int m = wm * 64 + i * 16 + l15;
            fa[i] = *(const half8_t*)&sA[m * LDK + k8];
            int nn = wn * 64 + i * 16 + l15;
            fb[i] = *(const half8_t*)&sB[nn * LDK + k8];
        }
        #pragma unroll
        for (int i = 0; i < 4; ++i)
            #pragma unroll
            for (int j = 0; j < 4; ++j)
                acc[i][j] = __builtin_amdgcn_mfma_f32_16x16x32_f16(fa[i], fb[j], acc[i][j], 0, 0, 0);
        __syncthreads();
    }

    const int r4 = (lane >> 4) * 4;
    #pragma unroll
    for (int j = 0; j < 4; ++j) {
        int col = n0 + wn * 64 + j * 16 + l15;
        float bv = bias[col];
        #pragma unroll
        for (int i = 0; i < 4; ++i) {
            #pragma unroll
            for (int r = 0; r < 4; ++r) {
                int row = m0 + wm * 64 + i * 16 + r4 + r;
                if (row < M) {
                    float v = fmaxf(acc[i][j][r] + bv, 0.f);
                    C16[(size_t)row * N + col] = (_Float16)v;
                }
            }
        }
    }
}

// ---------------- gemm2: fp16 MFMA, LDS-staged ----------------
__global__ __launch_bounds__(256) void gemm2_mfma(
        const _Float16* __restrict__ A16, const _Float16* __restrict__ B16,
        float* __restrict__ C, int M) {
    constexpr int K = 256, LDK = 40;
    __shared__ _Float16 sA[128 * LDK];
    __shared__ _Float16 sB[48 * LDK];
    const int t = threadIdx.x;
    const int m0 = blockIdx.x * 128;
    const int wave = t >> 6, lane = t & 63;
    const int l15 = lane & 15, k8 = (lane >> 4) * 8;

    f32x4_t acc[2][3] = {};

    for (int k0 = 0; k0 < K; k0 += 32) {
        #pragma unroll
        for (int u = 0; u < 2; ++u) {
            int idx = t + u * 256;
            int r = idx >> 2, c = (idx & 3) * 8;
            int gr = m0 + r; if (gr > M - 1) gr = M - 1;
            *(uint4*)&sA[r * LDK + c] = *(const uint4*)&A16[(size_t)gr * K + k0 + c];
        }
        if (t < 192) {
            int r = t >> 2, c = (t & 3) * 8;
            *(uint4*)&sB[r * LDK + c] = *(const uint4*)&B16[(size_t)r * K + k0 + c];
        }
        __syncthreads();
        half8_t fa[2], fb[3];
        #pragma unroll
        for (int i = 0; i < 2; ++i) {
            int m = wave * 32 + i * 16 + l15;
            fa[i] = *(const half8_t*)&sA[m * LDK + k8];
        }
        #pragma unroll
        for (int j = 0; j < 3; ++j) {
            int nn = j * 16 + l15;
            fb[j] = *(const half8_t*)&sB[nn * LDK + k8];
        }
        #pragma unroll
        for (int i = 0; i < 2; ++i)
            #pragma unroll
            for (int j = 0; j < 3; ++j)
                acc[i][j] = __builtin_amdgcn_mfma_f32_16x16x32_f16(fa[i], fb[j], acc[i][j], 0, 0, 0);
        __syncthreads();
    }

    const int r4 = (lane >> 4) * 4;
    #pragma unroll
    for (int i = 0; i < 2; ++i)
        #pragma unroll
        for (int j = 0; j < 3; ++j) {
            int col = j * 16 + l15;
            if (col < 40) {
                #pragma unroll
                for (int r = 0; r < 4; ++r) {
                    int row = m0 + wave * 32 + i * 16 + r4 + r;
                    if (row < M) C[(size_t)row * 40 + col] = acc[i][j][r];
                }
            }
        }
}

extern "C" void kernel_launch(void* const* d_in, const int* in_sizes, int n_in,
                              void* d_out, int out_size, void* d_ws, size_t ws_size,
                              hipStream_t stream) {
    const float* x   = (const float*)d_in[0];
    const int*   ei  = (const int*)d_in[1];
    const float* W1  = (const float*)d_in[2];
    const float* b1  = (const float*)d_in[3];
    const float* W2  = (const float*)d_in[4];
    const float* b2  = (const float*)d_in[5];
    const float* Wfc = (const float*)d_in[6];
    const float* bfc = (const float*)d_in[7];
    float* out = (float*)d_out;

    const int n = N_NODES, E = N_EDGES;
    const int* src = ei;
    const int* dst = ei + E;

    char* ws = (char*)d_ws;
    int*       deg    = (int*)(ws + 0);            // 400 KB
    float*     dinv   = (float*)(ws + 409600);     // 400 KB
    int*       rowptr = (int*)(ws + 819200);       // ~400 KB
    int*       bsums  = (int*)(ws + 1219584);      // 512 B
    float*     bfc2   = (float*)(ws + 1220096);    // 512 B
    _Float16*  w2t16  = (_Float16*)(ws + 1220608); // 24 KB [48][256]
    _Float16*  w1t16  = (_Float16*)(ws + 1245184); // 64 KB [256][128]
    int*       bcur   = (int*)(ws + 1310720);      // 100 KB (25000 cursors)
    int2*      csr    = (int2*)(ws + 1413120);     // 12.8 MB
    int2*      tmp    = (int2*)(ws + 14213120);    // 25.6 MB (bucket regions)
    _Float16*  x16    = (_Float16*)(ws + 39813120);  // 25.6 MB
    _Float16*  aggx16 = (_Float16*)(ws + 65413120);  // 25.6 MB
    _Float16*  h116   = (_Float16*)(ws + 91013120);  // 51.2 MB
    float*     h1w    = (float*)(ws + 142213120);    // 16 MB ([100k][40])

    const int nb = (n + 1023) / 1024;  // 98 scan blocks

    // ---- bucketed CSR build (XCD-sharded; no global-histogram atomics) ----
    bcur_init_kernel<<<(NBUCK * NGRP + 255) / 256, 256, 0, stream>>>(bcur, NBUCK * NGRP);
    bucket_kernel<<<(E + 255) / 256, 256, 0, stream>>>(src, dst, bcur, tmp, E);
    bdeg_kernel<<<NBUCK, 256, 0, stream>>>(bcur, tmp, deg, n);
    dinv_kernel<<<(n + 255) / 256, 256, 0, stream>>>(deg, dinv, n);
    scan_sums_kernel<<<nb, 256, 0, stream>>>(deg, bsums, n);
    scan_offsets_kernel<<<1, 128, 0, stream>>>(bsums, nb, rowptr + n);
    scan_final_kernel<<<nb, 256, 0, stream>>>(deg, bsums, rowptr, n);
    place_kernel<<<NBUCK, 256, 0, stream>>>(bcur, tmp, rowptr, dinv, csr, n);

    // ---- weight precomputes + x fp16 plane ----
    w2fc_kernel<<<1, 256, 0, stream>>>(W2, Wfc, b2, bfc, w2t16, bfc2);
    w1t_kernel<<<128, 256, 0, stream>>>(W1, w1t16);
    x16_kernel<<<(n * 128 / 4 + 255) / 256, 256, 0, stream>>>(x, x16, n * 32);

    // ---- layer 1: aggx(fp16) = A_hat @ x16; h1(fp16) = relu(aggx @ W1 + b1) ----
    gather1_kernel<<<2048, 256, 0, stream>>>(rowptr, csr, dinv, x16, aggx16, n);
    gemm1_mfma<<<dim3((n + 127) / 128, 2), 256, 0, stream>>>(
        aggx16, w1t16, b1, h116, n);

    // ---- layer 2 + FC folded: out = A_hat @ (h1 @ W2fc) + bfc2 ----
    gemm2_mfma<<<(n + 127) / 128, 256, 0, stream>>>(h116, w2t16, h1w, n);
    gather2_kernel<<<2048, 256, 0, stream>>>(rowptr, csr, dinv, h1w, bfc2, out, n);
}